// Round 1
// baseline (229.448 us; speedup 1.0000x reference)
//
#include <hip/hip_runtime.h>
#include <math.h>

typedef float f32x4 __attribute__((ext_vector_type(4)));
typedef short s8v __attribute__((ext_vector_type(8)));

#define LN_EPS 1e-6f

static __device__ __forceinline__ unsigned short f2bf(float f) {
  union { float f; unsigned int u; } v; v.f = f;
  unsigned int r = (v.u + 0x7FFFu + ((v.u >> 16) & 1u)) >> 16;
  return (unsigned short)r;
}
static __device__ __forceinline__ float bf2f(unsigned short b) {
  union { float f; unsigned int u; } v; v.u = ((unsigned int)b) << 16;
  return v.f;
}
static __device__ __forceinline__ float gelu_exact(float x) {
  return 0.5f * x * (1.0f + erff(x * 0.70710678118654752f));
}

// ---------------- prep: bf16 fragment-ordered weights + zero gacc ------------
// frag convention (consistent for A and B): lane l, elem j <-> k = kstep*32 + (l>>4)*8 + j
// B-frag: n = n0*16 + (l&15). Buffer layout: [n0][kstep][lane][8] bf16.
__global__ void prep_kernel(const float* __restrict__ w0, const float* __restrict__ w1,
                            const float* __restrict__ w2,
                            unsigned short* __restrict__ wt0f, unsigned short* __restrict__ w1f,
                            unsigned short* __restrict__ w2f, float* __restrict__ gacc) {
  int idx = blockIdx.x * blockDim.x + threadIdx.x;
  int stride = gridDim.x * blockDim.x;
  const int N0 = 65536, N1 = 16384, N2 = 8192, N3 = 2048;
  for (int i = idx; i < N0 + N1 + N2 + N3; i += stride) {
    if (i < N0) {               // w0: (256 out,256 in) -> 16 n0 x 8 kstep
      int j = i & 7, l = (i >> 3) & 63, ks = (i >> 9) & 7, n0 = i >> 12;
      wt0f[i] = f2bf(w0[(n0 * 16 + (l & 15)) * 256 + ks * 32 + (l >> 4) * 8 + j]);
    } else if (i < N0 + N1) {   // w1 local half: (128 out, first 128 in) -> 8 n0 x 4 kstep
      int t = i - N0;
      int j = t & 7, l = (t >> 3) & 63, ks = (t >> 9) & 3, n0 = t >> 11;
      w1f[t] = f2bf(w1[(n0 * 16 + (l & 15)) * 256 + ks * 32 + (l >> 4) * 8 + j]);
    } else if (i < N0 + N1 + N2) { // w2: (64 out, 128 in) -> 4 n0 x 4 kstep
      int t = i - N0 - N1;
      int j = t & 7, l = (t >> 3) & 63, ks = (t >> 9) & 3, n0 = t >> 11;
      w2f[t] = f2bf(w2[(n0 * 16 + (l & 15)) * 128 + ks * 32 + (l >> 4) * 8 + j]);
    } else {
      gacc[i - N0 - N1 - N2] = 0.0f;   // 16 batches x 128 ch
    }
  }
}

// ---------------- k1: LN + conv0 + gelu; local->yl, global->atomic sums ------
// 64 pixels/block, 256 threads (4 waves). GEMM M=64 (pixels) N=256 (out) K=256 (ch).
__global__ __launch_bounds__(256, 2) void k1_kernel(
    const float* __restrict__ dec, const float* __restrict__ enc,
    const float* __restrict__ lnw, const float* __restrict__ lnb,
    const float* __restrict__ b0, const unsigned short* __restrict__ wt0f,
    unsigned short* __restrict__ yl, float* __restrict__ gacc) {
  __shared__ __align__(16) unsigned char At[64 * 512];   // [p][c] bf16, XOR-swizzled, 32 KiB
  __shared__ float red[16][16][8];                       // 8 KiB partial LN sums
  __shared__ float muL[64], rsL[64];
  __shared__ float lnwS[256], lnbS[256];

  const int tid = threadIdx.x;
  const int blk = blockIdx.x;
  const int b = blk >> 8;              // 256 blocks per batch image
  const int hw0 = (blk & 255) << 6;    // 64 pixels
  const int g = tid >> 4, kq = tid & 15;
  const int lane = tid & 63, w = tid >> 6;
  const int l15 = lane & 15, lg = lane >> 4;

  lnwS[tid] = lnw[tid];
  lnbS[tid] = lnb[tid];

  // ---- pass A: x = dec + enc, per-pixel partial sums; x kept in regs --------
  // thread owns channels {it*128 + g*8 + s} x 4 pixels (kq*4 .. kq*4+3)
  f32x4 xv[16];
  f32x4 sum = {0.f, 0.f, 0.f, 0.f}, sq = {0.f, 0.f, 0.f, 0.f};
  const int baseoff = (b * 256) * 16384 + hw0 + (kq << 2);
#pragma unroll
  for (int it = 0; it < 2; ++it) {
#pragma unroll
    for (int s = 0; s < 8; ++s) {
      int c = it * 128 + g * 8 + s;
      f32x4 d = *(const f32x4*)(dec + baseoff + c * 16384);
      f32x4 e = *(const f32x4*)(enc + baseoff + c * 16384);
      f32x4 x = d + e;
      xv[it * 8 + s] = x;
      sum += x;
      sq += x * x;
    }
  }
#pragma unroll
  for (int q = 0; q < 4; ++q) { red[g][kq][q] = sum[q]; red[g][kq][4 + q] = sq[q]; }
  __syncthreads();
  if (tid < 64) {
    int p = tid, kk = p >> 2, comp = p & 3;
    float s = 0.f, s2 = 0.f;
#pragma unroll
    for (int gg = 0; gg < 16; ++gg) { s += red[gg][kk][comp]; s2 += red[gg][kk][4 + comp]; }
    float mu = s * (1.0f / 256.0f);
    float var = s2 * (1.0f / 256.0f) - mu * mu;
    muL[p] = mu;
    rsL[p] = rsqrtf(var + LN_EPS);
  }
  __syncthreads();

  // ---- normalize -> bf16 A-tile (swizzled [p][c]) ---------------------------
#pragma unroll
  for (int it = 0; it < 2; ++it) {
    int c0 = it * 128 + g * 8;
#pragma unroll
    for (int px = 0; px < 4; ++px) {
      int p = (kq << 2) + px;
      float mu = muL[p], rs = rsL[p];
      s8v hv;
#pragma unroll
      for (int s = 0; s < 8; ++s) {
        float x = xv[it * 8 + s][px];
        hv[s] = (short)f2bf((x - mu) * rs * lnwS[c0 + s] + lnbS[c0 + s]);
      }
      int byte = (p * 512 + c0 * 2) ^ ((p & 7) << 4);
      *(s8v*)(&At[byte]) = hv;
    }
  }
  __syncthreads();

  // ---- GEMM: wave w -> output cols [64w, 64w+64) ----------------------------
  f32x4 acc[4][4];
#pragma unroll
  for (int mi = 0; mi < 4; ++mi)
#pragma unroll
    for (int ni = 0; ni < 4; ++ni) acc[mi][ni] = (f32x4){0.f, 0.f, 0.f, 0.f};

#pragma unroll
  for (int ks = 0; ks < 8; ++ks) {
    s8v a[4];
#pragma unroll
    for (int mi = 0; mi < 4; ++mi) {
      int p = mi * 16 + l15;
      int byte = (p * 512 + ks * 64 + lg * 16) ^ ((p & 7) << 4);
      a[mi] = *(const s8v*)(&At[byte]);
    }
#pragma unroll
    for (int ni = 0; ni < 4; ++ni) {
      int n0 = w * 4 + ni;
      s8v bfr = *(const s8v*)(wt0f + ((n0 * 8 + ks) * 64 + lane) * 8);
#pragma unroll
      for (int mi = 0; mi < 4; ++mi)
        acc[mi][ni] = __builtin_amdgcn_mfma_f32_16x16x32_bf16(a[mi], bfr, acc[mi][ni], 0, 0, 0);
    }
  }

  // ---- epilogue: + b0, gelu; waves 0-1 store local, waves 2-3 reduce global -
  float bias[4];
#pragma unroll
  for (int ni = 0; ni < 4; ++ni) bias[ni] = b0[w * 64 + ni * 16 + l15];

  if (w < 2) {
#pragma unroll
    for (int mi = 0; mi < 4; ++mi) {
#pragma unroll
      for (int r = 0; r < 4; ++r) {
        int p = mi * 16 + lg * 4 + r;
        int prow = (b * 16384 + hw0 + p) * 128;
#pragma unroll
        for (int ni = 0; ni < 4; ++ni) {
          float v = gelu_exact(acc[mi][ni][r] + bias[ni]);
          yl[prow + w * 64 + ni * 16 + l15] = f2bf(v);
        }
      }
    }
  } else {
#pragma unroll
    for (int ni = 0; ni < 4; ++ni) {
      float ps = 0.f;
#pragma unroll
      for (int mi = 0; mi < 4; ++mi)
#pragma unroll
        for (int r = 0; r < 4; ++r)
          ps += gelu_exact(acc[mi][ni][r] + bias[ni]);
      ps += __shfl_xor(ps, 16, 64);
      ps += __shfl_xor(ps, 32, 64);
      if (lane < 16) atomicAdd(&gacc[b * 128 + (w - 2) * 64 + ni * 16 + lane], ps);
    }
  }
}

// ---------------- kmid: fold global mean + b1 into per-batch conv1 bias ------
__global__ void kmid_kernel(const float* __restrict__ w1, const float* __restrict__ b1,
                            const float* __restrict__ gacc, float* __restrict__ g1) {
  int b = blockIdx.x, o = threadIdx.x;   // 16 x 128
  float acc = b1[o];
  const float inv = 1.0f / 16384.0f;
  for (int c = 0; c < 128; ++c)
    acc += w1[o * 256 + 128 + c] * (gacc[b * 128 + c] * inv);
  g1[b * 128 + o] = acc;
}

// ---------------- k2: conv1+gelu, conv2+gelu, conv3+sigmoid ------------------
__global__ __launch_bounds__(256, 4) void k2_kernel(
    const unsigned short* __restrict__ yl, const float* __restrict__ g1,
    const float* __restrict__ b2v, const float* __restrict__ w3,
    const float* __restrict__ b3, const unsigned short* __restrict__ w1f,
    const unsigned short* __restrict__ w2f, float* __restrict__ out) {
  __shared__ __align__(16) unsigned char Yt[64 * 256];   // 16 KiB  [p][c<128] bf16 swz
  __shared__ __align__(16) unsigned char Z1[64 * 256];   // 16 KiB
  __shared__ __align__(16) unsigned char Z2[64 * 128];   // 8 KiB
  __shared__ float part3[4][64];
  __shared__ float w3S[64];

  const int tid = threadIdx.x, blk = blockIdx.x;
  const int lane = tid & 63, w = tid >> 6, l15 = lane & 15, lg = lane >> 4;
  const int P0 = blk * 64;
  const int b = blk >> 8;

  if (tid < 64) w3S[tid] = w3[tid];

  // stage yl tile: read linear global rows, write swizzled LDS
#pragma unroll
  for (int q = 0; q < 4; ++q) {
    int p = q * 16 + (tid >> 4);
    int c2 = (tid & 15) * 16;   // byte column, 16-aligned
    s8v v = *(const s8v*)((const char*)yl + (long)(P0 + p) * 256 + c2);
    int byte = (p * 256 + c2) ^ ((p & 7) << 4);
    *(s8v*)(&Yt[byte]) = v;
  }
  __syncthreads();

  // ---- conv1: N=128, wave w -> cols [32w, 32w+32), K=128 --------------------
  f32x4 acc1[4][2];
#pragma unroll
  for (int mi = 0; mi < 4; ++mi)
#pragma unroll
    for (int ni = 0; ni < 2; ++ni) acc1[mi][ni] = (f32x4){0.f, 0.f, 0.f, 0.f};
#pragma unroll
  for (int ks = 0; ks < 4; ++ks) {
    s8v a[4];
#pragma unroll
    for (int mi = 0; mi < 4; ++mi) {
      int p = mi * 16 + l15;
      int byte = (p * 256 + ks * 64 + lg * 16) ^ ((p & 7) << 4);
      a[mi] = *(const s8v*)(&Yt[byte]);
    }
#pragma unroll
    for (int ni = 0; ni < 2; ++ni) {
      int n0 = w * 2 + ni;
      s8v bfr = *(const s8v*)(w1f + ((n0 * 4 + ks) * 64 + lane) * 8);
#pragma unroll
      for (int mi = 0; mi < 4; ++mi)
        acc1[mi][ni] = __builtin_amdgcn_mfma_f32_16x16x32_bf16(a[mi], bfr, acc1[mi][ni], 0, 0, 0);
    }
  }
#pragma unroll
  for (int ni = 0; ni < 2; ++ni) {
    int o = (w * 2 + ni) * 16 + l15;
    float bias = g1[b * 128 + o];
#pragma unroll
    for (int mi = 0; mi < 4; ++mi)
#pragma unroll
      for (int r = 0; r < 4; ++r) {
        int p = mi * 16 + lg * 4 + r;
        float v = gelu_exact(acc1[mi][ni][r] + bias);
        int byte = (p * 256 + o * 2) ^ ((p & 7) << 4);
        *(unsigned short*)(&Z1[byte]) = f2bf(v);
      }
  }
  __syncthreads();

  // ---- conv2: N=64, wave w -> cols [16w, 16w+16), K=128 ---------------------
  f32x4 acc2[4];
#pragma unroll
  for (int mi = 0; mi < 4; ++mi) acc2[mi] = (f32x4){0.f, 0.f, 0.f, 0.f};
#pragma unroll
  for (int ks = 0; ks < 4; ++ks) {
    s8v a[4];
#pragma unroll
    for (int mi = 0; mi < 4; ++mi) {
      int p = mi * 16 + l15;
      int byte = (p * 256 + ks * 64 + lg * 16) ^ ((p & 7) << 4);
      a[mi] = *(const s8v*)(&Z1[byte]);
    }
    s8v bfr = *(const s8v*)(w2f + ((w * 4 + ks) * 64 + lane) * 8);
#pragma unroll
    for (int mi = 0; mi < 4; ++mi)
      acc2[mi] = __builtin_amdgcn_mfma_f32_16x16x32_bf16(a[mi], bfr, acc2[mi], 0, 0, 0);
  }
  {
    int o = w * 16 + l15;
    float bias = b2v[o];
#pragma unroll
    for (int mi = 0; mi < 4; ++mi)
#pragma unroll
      for (int r = 0; r < 4; ++r) {
        int p = mi * 16 + lg * 4 + r;
        float v = gelu_exact(acc2[mi][r] + bias);
        int byte = (p * 128 + o * 2) ^ ((p & 7) << 4);
        *(unsigned short*)(&Z2[byte]) = f2bf(v);
      }
  }
  __syncthreads();

  // ---- conv3 (dot-64) + sigmoid --------------------------------------------
  {
    int p = tid & 63, cg = tid >> 6;
    float dot = 0.f;
#pragma unroll
    for (int half = 0; half < 2; ++half) {
      int byte = (p * 128 + cg * 32 + half * 16) ^ ((p & 7) << 4);
      s8v z = *(const s8v*)(&Z2[byte]);
#pragma unroll
      for (int j = 0; j < 8; ++j)
        dot += bf2f((unsigned short)z[j]) * w3S[cg * 16 + half * 8 + j];
    }
    part3[cg][p] = dot;
  }
  __syncthreads();
  if (tid < 64) {
    float t = part3[0][tid] + part3[1][tid] + part3[2][tid] + part3[3][tid] + b3[0];
    out[P0 + tid] = 1.0f / (1.0f + expf(-t));
  }
}

// ---------------- launch -----------------------------------------------------
extern "C" void kernel_launch(void* const* d_in, const int* in_sizes, int n_in,
                              void* d_out, int out_size, void* d_ws, size_t ws_size,
                              hipStream_t stream) {
  const float* dec = (const float*)d_in[0];
  const float* enc = (const float*)d_in[1];
  const float* lnw = (const float*)d_in[2];
  const float* lnb = (const float*)d_in[3];
  const float* w0  = (const float*)d_in[4];
  const float* b0  = (const float*)d_in[5];
  const float* w1  = (const float*)d_in[6];
  const float* b1  = (const float*)d_in[7];
  const float* w2  = (const float*)d_in[8];
  const float* b2  = (const float*)d_in[9];
  const float* w3  = (const float*)d_in[10];
  const float* b3  = (const float*)d_in[11];

  char* ws = (char*)d_ws;
  unsigned short* yl   = (unsigned short*)ws;                   // 67108864 B
  unsigned short* wt0f = (unsigned short*)(ws + 67108864);      // 131072 B
  unsigned short* w1f  = (unsigned short*)(ws + 67239936);      // 32768 B
  unsigned short* w2f  = (unsigned short*)(ws + 67272704);      // 16384 B
  float* gacc          = (float*)(ws + 67289088);               // 8192 B
  float* g1            = (float*)(ws + 67297280);               // 8192 B
  // total ws use: 67305472 B (~64.2 MiB)

  prep_kernel<<<128, 256, 0, stream>>>(w0, w1, w2, wt0f, w1f, w2f, gacc);
  k1_kernel<<<4096, 256, 0, stream>>>(dec, enc, lnw, lnb, b0, wt0f, yl, gacc);
  kmid_kernel<<<16, 128, 0, stream>>>(w1, b1, gacc, g1);
  k2_kernel<<<4096, 256, 0, stream>>>(yl, g1, b2, w3, b3, w1f, w2f, (float*)d_out);
}